// Round 1
// baseline (3651.609 us; speedup 1.0000x reference)
//
#include <hip/hip_runtime.h>
#include <hip/hip_bf16.h>

#define GG 128   // num_graphs (static in problem)

// ---------------- degree count ----------------
__global__ __launch_bounds__(256) void deg_kernel(const int* __restrict__ ei,
                                                  float* __restrict__ degf,
                                                  float* __restrict__ degb, int e) {
    int i = blockIdx.x * 256 + threadIdx.x;
    if (i >= e) return;
    atomicAdd(degf + ei[e + i], 1.f);  // in-degree of dst (forward agg)
    atomicAdd(degb + ei[i], 1.f);      // out-degree of src (backward agg)
}

__global__ __launch_bounds__(256) void inv_kernel(const float* __restrict__ degf,
                                                  const float* __restrict__ degb,
                                                  float* __restrict__ invf,
                                                  float* __restrict__ invb, int n) {
    int i = blockIdx.x * 256 + threadIdx.x;
    if (i >= n) return;
    invf[i] = 1.f / fmaxf(degf[i], 1.f);
    invb[i] = 1.f / fmaxf(degb[i], 1.f);
}

// ---------------- edge scatter (both directions) ----------------
// 16 threads per edge; each thread handles one float4 chunk of the 64-dim row.
__global__ __launch_bounds__(256) void scatter_edges(const float* __restrict__ X,
                                                     const int* __restrict__ ei,
                                                     float* __restrict__ aggf,
                                                     float* __restrict__ aggb, int e) {
    int tid = blockIdx.x * 256 + threadIdx.x;
    int edge = tid >> 4;
    if (edge >= e) return;
    int c = (tid & 15) * 4;
    int s = ei[edge];
    int d = ei[e + edge];
    float4 xs = *reinterpret_cast<const float4*>(X + (size_t)s * 64 + c);
    float4 xd = *reinterpret_cast<const float4*>(X + (size_t)d * 64 + c);
    float* pf = aggf + (size_t)d * 64 + c;
    float* pb = aggb + (size_t)s * 64 + c;
    atomicAdd(pf + 0, xs.x); atomicAdd(pf + 1, xs.y);
    atomicAdd(pf + 2, xs.z); atomicAdd(pf + 3, xs.w);
    atomicAdd(pb + 0, xd.x); atomicAdd(pb + 1, xd.y);
    atomicAdd(pb + 2, xd.z); atomicAdd(pb + 3, xd.w);
}

// ---------------- fused bidirectional SAGE layer ----------------
// out = relu(0.5*(mean_f@Wlf^T + mean_b@Wlb^T + x@(Wrf+Wrb)^T + blf+blb))
// 64-node tile per block, 256 threads, 4x4 register tile per thread,
// 3 K-passes (mean_f, mean_b, x) reusing 2 x 17KB LDS buffers.
__global__ __launch_bounds__(256) void fused_sage(
    const float* __restrict__ X,
    const float* __restrict__ aggf, const float* __restrict__ aggb,
    const float* __restrict__ invf, const float* __restrict__ invb,
    const float* __restrict__ Wlf, const float* __restrict__ blf,
    const float* __restrict__ Wrf,
    const float* __restrict__ Wlb, const float* __restrict__ blb,
    const float* __restrict__ Wrb,
    float* __restrict__ Out, int n)
{
    __shared__ float sIn[64][68];
    __shared__ float sW[64][68];
    const int t = threadIdx.x;
    const int base = blockIdx.x * 64;
    const int jg = t & 15;   // output-col group (strided by 16)
    const int ng = t >> 4;   // node-row group (strided by 16)

    float acc[4][4];
#pragma unroll
    for (int a = 0; a < 4; a++)
#pragma unroll
        for (int b = 0; b < 4; b++) acc[a][b] = 0.f;

    for (int p = 0; p < 3; p++) {
        const float* src = (p == 0) ? aggf : (p == 1) ? aggb : X;
        const float* inv = (p == 0) ? invf : invb;
        // stage 64x64 input rows (scaled by 1/deg for agg passes)
#pragma unroll
        for (int i = 0; i < 4; i++) {
            int f4 = t + 256 * i;          // 0..1023 float4s
            int row = f4 >> 4, c4 = f4 & 15;
            int grow = base + row;
            float4 v = make_float4(0.f, 0.f, 0.f, 0.f);
            if (grow < n) {
                v = *reinterpret_cast<const float4*>(src + (size_t)grow * 64 + c4 * 4);
                if (p < 2) {
                    float s = inv[grow];
                    v.x *= s; v.y *= s; v.z *= s; v.w *= s;
                }
            }
            *reinterpret_cast<float4*>(&sIn[row][c4 * 4]) = v;
        }
        // stage weights (pass 2 stages Wrf+Wrb)
#pragma unroll
        for (int i = 0; i < 4; i++) {
            int f4 = t + 256 * i;
            int row = f4 >> 4, c4 = f4 & 15;
            float4 w;
            if (p == 0) w = *reinterpret_cast<const float4*>(Wlf + row * 64 + c4 * 4);
            else if (p == 1) w = *reinterpret_cast<const float4*>(Wlb + row * 64 + c4 * 4);
            else {
                float4 w1 = *reinterpret_cast<const float4*>(Wrf + row * 64 + c4 * 4);
                float4 w2 = *reinterpret_cast<const float4*>(Wrb + row * 64 + c4 * 4);
                w = make_float4(w1.x + w2.x, w1.y + w2.y, w1.z + w2.z, w1.w + w2.w);
            }
            *reinterpret_cast<float4*>(&sW[row][c4 * 4]) = w;
        }
        __syncthreads();
        // compute
        for (int kc = 0; kc < 16; kc++) {
            float4 av[4], wv[4];
#pragma unroll
            for (int i = 0; i < 4; i++)
                av[i] = *reinterpret_cast<const float4*>(&sIn[ng + 16 * i][kc * 4]);
#pragma unroll
            for (int i = 0; i < 4; i++)
                wv[i] = *reinterpret_cast<const float4*>(&sW[jg + 16 * i][kc * 4]);
#pragma unroll
            for (int a = 0; a < 4; a++)
#pragma unroll
                for (int b = 0; b < 4; b++)
                    acc[a][b] += av[a].x * wv[b].x + av[a].y * wv[b].y +
                                 av[a].z * wv[b].z + av[a].w * wv[b].w;
        }
        __syncthreads();
    }
    // epilogue: bias + relu + store
#pragma unroll
    for (int b = 0; b < 4; b++) {
        int j = jg + 16 * b;
        float bias = 0.5f * (blf[j] + blb[j]);
#pragma unroll
        for (int a = 0; a < 4; a++) {
            int grow = base + ng + 16 * a;
            if (grow < n) {
                float v = 0.5f * acc[a][b] + bias;
                Out[(size_t)grow * 64 + j] = v > 0.f ? v : 0.f;
            }
        }
    }
}

// ---------------- pooling: per-block LDS [G][64] accumulator ----------------
__global__ __launch_bounds__(256) void pool_partial(const float* __restrict__ H,
                                                    const int* __restrict__ batch,
                                                    float* __restrict__ psum,
                                                    float* __restrict__ pcnt, int n) {
    __shared__ float ls[GG * 64];
    __shared__ float lc[GG];
    int t = threadIdx.x;
    for (int i = t; i < GG * 64; i += 256) ls[i] = 0.f;
    for (int i = t; i < GG; i += 256) lc[i] = 0.f;
    __syncthreads();
    int chunk = (n + gridDim.x - 1) / gridDim.x;
    int base = blockIdx.x * chunk;
    int end = base + chunk; if (end > n) end = n;
    int f = t & 63, r = t >> 6;  // r in 0..3
    for (int node = base + r; node < end; node += 4) {
        int g = batch[node];
        float v = H[(size_t)node * 64 + f];
        atomicAdd(&ls[g * 64 + f], v);
        if (f == 0) atomicAdd(&lc[g], 1.f);
    }
    __syncthreads();
    for (int i = t; i < GG * 64; i += 256) {
        float v = ls[i];
        if (v != 0.f) atomicAdd(&psum[i], v);
    }
    for (int i = t; i < GG; i += 256) {
        float v = lc[i];
        if (v != 0.f) atomicAdd(&pcnt[i], v);
    }
}

// ---------------- head: out[g][o] = (psum[g]/cnt) . pred_W[o] + pred_b[o] ----
__global__ __launch_bounds__(256) void pool_final(const float* __restrict__ psum,
                                                  const float* __restrict__ pcnt,
                                                  const float* __restrict__ PW,
                                                  const float* __restrict__ Pb,
                                                  float* __restrict__ out) {
    int t = blockIdx.x * 256 + threadIdx.x;  // 0..2047
    int g = t >> 4, o = t & 15;
    if (g >= GG) return;
    float inv = 1.f / fmaxf(pcnt[g], 1.f);
    float acc = 0.f;
#pragma unroll 8
    for (int k = 0; k < 64; k++) acc += psum[g * 64 + k] * PW[o * 64 + k];
    out[t] = acc * inv + Pb[o];
}

extern "C" void kernel_launch(void* const* d_in, const int* in_sizes, int n_in,
                              void* d_out, int out_size, void* d_ws, size_t ws_size,
                              hipStream_t stream) {
    const float* x      = (const float*)d_in[0];
    const int*   ei     = (const int*)d_in[1];
    const int*   batch  = (const int*)d_in[2];
    const float* l0f_Wl = (const float*)d_in[4];
    const float* l0f_bl = (const float*)d_in[5];
    const float* l0f_Wr = (const float*)d_in[6];
    const float* l0b_Wl = (const float*)d_in[7];
    const float* l0b_bl = (const float*)d_in[8];
    const float* l0b_Wr = (const float*)d_in[9];
    const float* l1f_Wl = (const float*)d_in[10];
    const float* l1f_bl = (const float*)d_in[11];
    const float* l1f_Wr = (const float*)d_in[12];
    const float* l1b_Wl = (const float*)d_in[13];
    const float* l1b_bl = (const float*)d_in[14];
    const float* l1b_Wr = (const float*)d_in[15];
    const float* pred_W = (const float*)d_in[16];
    const float* pred_b = (const float*)d_in[17];

    const int n = in_sizes[0] / 64;
    const int e = in_sizes[1] / 2;
    const size_t N64 = (size_t)n * 64;

    float* ws   = (float*)d_ws;
    float* aggf = ws;                 // [n][64]
    float* aggb = ws + N64;           // [n][64]
    float* degf = ws + 2 * N64;       // [n]
    float* degb = degf + n;           // [n]
    float* psum = degb + n;           // [G][64]
    float* pcnt = psum + GG * 64;     // [G]
    size_t zcount = 2 * N64 + 2 * (size_t)n + GG * 64 + GG;
    float* h0   = ws + ((zcount + 15) & ~(size_t)15);  // [n][64]
    float* invf = h0 + N64;           // [n]
    float* invb = invf + n;           // [n]
    float* h1   = aggf;               // alias (safe: blocks read rows to LDS before writing)

    // zero accumulators (aggf, aggb, degf, degb, psum, pcnt)
    hipMemsetAsync(ws, 0, zcount * sizeof(float), stream);

    deg_kernel<<<(e + 255) / 256, 256, 0, stream>>>(ei, degf, degb, e);
    inv_kernel<<<(n + 255) / 256, 256, 0, stream>>>(degf, degb, invf, invb, n);

    // layer 0
    scatter_edges<<<((size_t)e * 16 + 255) / 256, 256, 0, stream>>>(x, ei, aggf, aggb, e);
    fused_sage<<<(n + 63) / 64, 256, 0, stream>>>(x, aggf, aggb, invf, invb,
        l0f_Wl, l0f_bl, l0f_Wr, l0b_Wl, l0b_bl, l0b_Wr, h0, n);

    // layer 1
    hipMemsetAsync(aggf, 0, 2 * N64 * sizeof(float), stream);
    scatter_edges<<<((size_t)e * 16 + 255) / 256, 256, 0, stream>>>(h0, ei, aggf, aggb, e);
    fused_sage<<<(n + 63) / 64, 256, 0, stream>>>(h0, aggf, aggb, invf, invb,
        l1f_Wl, l1f_bl, l1f_Wr, l1b_Wl, l1b_bl, l1b_Wr, h1, n);

    // pooling + head
    pool_partial<<<256, 256, 0, stream>>>(h1, batch, psum, pcnt, n);
    pool_final<<<8, 256, 0, stream>>>(psum, pcnt, pred_W, pred_b, (float*)d_out);
}

// Round 2
// 589.799 us; speedup vs baseline: 6.1913x; 6.1913x over previous
//
#include <hip/hip_runtime.h>
#include <hip/hip_bf16.h>

#define GG 128   // num_graphs (static in problem)

// ---------------- degree count (int atomics) ----------------
__global__ __launch_bounds__(256) void deg_kernel(const int* __restrict__ ei,
                                                  int* __restrict__ degf,
                                                  int* __restrict__ degb, int e) {
    int i = blockIdx.x * 256 + threadIdx.x;
    if (i >= e) return;
    atomicAdd(degf + ei[e + i], 1);  // in-degree of dst (forward agg)
    atomicAdd(degb + ei[i], 1);      // out-degree of src (backward agg)
}

// ---------------- 3-phase exclusive scan over n (n <= 512*256) --------------
__global__ __launch_bounds__(256) void scan1(const int* __restrict__ deg,
                                             int* __restrict__ partial, int n) {
    __shared__ int s[256];
    int t = threadIdx.x, i = blockIdx.x * 256 + t;
    s[t] = (i < n) ? deg[i] : 0;
    __syncthreads();
    for (int o = 128; o > 0; o >>= 1) {
        if (t < o) s[t] += s[t + o];
        __syncthreads();
    }
    if (t == 0) partial[blockIdx.x] = s[0];
}

__global__ __launch_bounds__(512) void scan2(int* __restrict__ partial, int nb) {
    __shared__ int s[512];
    int t = threadIdx.x;
    int v = (t < nb) ? partial[t] : 0;
    s[t] = v;
    __syncthreads();
    for (int o = 1; o < 512; o <<= 1) {
        int u = (t >= o) ? s[t - o] : 0;
        __syncthreads();
        s[t] += u;
        __syncthreads();
    }
    if (t < nb) partial[t] = s[t] - v;  // exclusive
}

__global__ __launch_bounds__(256) void scan3(const int* __restrict__ deg,
                                             const int* __restrict__ partial,
                                             int* __restrict__ off, int n, int e) {
    __shared__ int s[256];
    int t = threadIdx.x, i = blockIdx.x * 256 + t;
    int v = (i < n) ? deg[i] : 0;
    s[t] = v;
    __syncthreads();
    for (int o = 1; o < 256; o <<= 1) {
        int u = (t >= o) ? s[t - o] : 0;
        __syncthreads();
        s[t] += u;
        __syncthreads();
    }
    if (i < n) off[i] = partial[blockIdx.x] + s[t] - v;
    if (i == n - 1) off[n] = e;
}

// ---------------- cursors + inverse degrees ----------------
__global__ __launch_bounds__(256) void init_cur_inv(
    const int* __restrict__ off_f, const int* __restrict__ off_b,
    const int* __restrict__ degf, const int* __restrict__ degb,
    int* __restrict__ cur_f, int* __restrict__ cur_b,
    float* __restrict__ invf, float* __restrict__ invb, int n) {
    int i = blockIdx.x * 256 + threadIdx.x;
    if (i >= n) return;
    cur_f[i] = off_f[i];
    cur_b[i] = off_b[i];
    invf[i] = 1.f / fmaxf((float)degf[i], 1.f);
    invb[i] = 1.f / fmaxf((float)degb[i], 1.f);
}

// ---------------- CSR fill ----------------
__global__ __launch_bounds__(256) void fill_csr(const int* __restrict__ ei,
                                                int* __restrict__ cur_f,
                                                int* __restrict__ cur_b,
                                                int* __restrict__ csr_f,
                                                int* __restrict__ csr_b, int e) {
    int i = blockIdx.x * 256 + threadIdx.x;
    if (i >= e) return;
    int s = ei[i], d = ei[e + i];
    csr_f[atomicAdd(&cur_f[d], 1)] = s;   // forward: neighbors contributing to d
    csr_b[atomicAdd(&cur_b[s], 1)] = d;   // backward: neighbors contributing to s
}

// ---------------- gather-mean (both directions), 16 lanes per node ----------
__global__ __launch_bounds__(256) void gather_mean(
    const float* __restrict__ X,
    const int* __restrict__ off_f, const int* __restrict__ csr_f,
    const float* __restrict__ invf,
    const int* __restrict__ off_b, const int* __restrict__ csr_b,
    const float* __restrict__ invb,
    float* __restrict__ aggf, float* __restrict__ aggb, int n) {
    int tid = blockIdx.x * 256 + threadIdx.x;
    int node = tid >> 4;
    if (node >= n) return;
    int c = (tid & 15) * 4;
    {
        int b = off_f[node], en = off_f[node + 1];
        float4 acc = make_float4(0.f, 0.f, 0.f, 0.f);
        for (int k = b; k < en; k++) {
            int s = csr_f[k];
            float4 v = *reinterpret_cast<const float4*>(X + (size_t)s * 64 + c);
            acc.x += v.x; acc.y += v.y; acc.z += v.z; acc.w += v.w;
        }
        float iv = invf[node];
        float4 r = make_float4(acc.x * iv, acc.y * iv, acc.z * iv, acc.w * iv);
        *reinterpret_cast<float4*>(aggf + (size_t)node * 64 + c) = r;
    }
    {
        int b = off_b[node], en = off_b[node + 1];
        float4 acc = make_float4(0.f, 0.f, 0.f, 0.f);
        for (int k = b; k < en; k++) {
            int s = csr_b[k];
            float4 v = *reinterpret_cast<const float4*>(X + (size_t)s * 64 + c);
            acc.x += v.x; acc.y += v.y; acc.z += v.z; acc.w += v.w;
        }
        float iv = invb[node];
        float4 r = make_float4(acc.x * iv, acc.y * iv, acc.z * iv, acc.w * iv);
        *reinterpret_cast<float4*>(aggb + (size_t)node * 64 + c) = r;
    }
}

// ---------------- fused bidirectional SAGE layer ----------------
// out = relu(0.5*(mean_f@Wlf^T + mean_b@Wlb^T + x@(Wrf+Wrb)^T + blf+blb))
__global__ __launch_bounds__(256) void fused_sage(
    const float* __restrict__ X,
    const float* __restrict__ aggf, const float* __restrict__ aggb,
    const float* __restrict__ Wlf, const float* __restrict__ blf,
    const float* __restrict__ Wrf,
    const float* __restrict__ Wlb, const float* __restrict__ blb,
    const float* __restrict__ Wrb,
    float* __restrict__ Out, int n)
{
    __shared__ float sIn[64][68];
    __shared__ float sW[64][68];
    const int t = threadIdx.x;
    const int base = blockIdx.x * 64;
    const int jg = t & 15;   // output-col group (strided by 16)
    const int ng = t >> 4;   // node-row group (strided by 16)

    float acc[4][4];
#pragma unroll
    for (int a = 0; a < 4; a++)
#pragma unroll
        for (int b = 0; b < 4; b++) acc[a][b] = 0.f;

    for (int p = 0; p < 3; p++) {
        const float* src = (p == 0) ? aggf : (p == 1) ? aggb : X;
#pragma unroll
        for (int i = 0; i < 4; i++) {
            int f4 = t + 256 * i;
            int row = f4 >> 4, c4 = f4 & 15;
            int grow = base + row;
            float4 v = make_float4(0.f, 0.f, 0.f, 0.f);
            if (grow < n)
                v = *reinterpret_cast<const float4*>(src + (size_t)grow * 64 + c4 * 4);
            *reinterpret_cast<float4*>(&sIn[row][c4 * 4]) = v;
        }
#pragma unroll
        for (int i = 0; i < 4; i++) {
            int f4 = t + 256 * i;
            int row = f4 >> 4, c4 = f4 & 15;
            float4 w;
            if (p == 0) w = *reinterpret_cast<const float4*>(Wlf + row * 64 + c4 * 4);
            else if (p == 1) w = *reinterpret_cast<const float4*>(Wlb + row * 64 + c4 * 4);
            else {
                float4 w1 = *reinterpret_cast<const float4*>(Wrf + row * 64 + c4 * 4);
                float4 w2 = *reinterpret_cast<const float4*>(Wrb + row * 64 + c4 * 4);
                w = make_float4(w1.x + w2.x, w1.y + w2.y, w1.z + w2.z, w1.w + w2.w);
            }
            *reinterpret_cast<float4*>(&sW[row][c4 * 4]) = w;
        }
        __syncthreads();
        for (int kc = 0; kc < 16; kc++) {
            float4 av[4], wv[4];
#pragma unroll
            for (int i = 0; i < 4; i++)
                av[i] = *reinterpret_cast<const float4*>(&sIn[ng + 16 * i][kc * 4]);
#pragma unroll
            for (int i = 0; i < 4; i++)
                wv[i] = *reinterpret_cast<const float4*>(&sW[jg + 16 * i][kc * 4]);
#pragma unroll
            for (int a = 0; a < 4; a++)
#pragma unroll
                for (int b = 0; b < 4; b++)
                    acc[a][b] += av[a].x * wv[b].x + av[a].y * wv[b].y +
                                 av[a].z * wv[b].z + av[a].w * wv[b].w;
        }
        __syncthreads();
    }
#pragma unroll
    for (int b = 0; b < 4; b++) {
        int j = jg + 16 * b;
        float bias = 0.5f * (blf[j] + blb[j]);
#pragma unroll
        for (int a = 0; a < 4; a++) {
            int grow = base + ng + 16 * a;
            if (grow < n) {
                float v = 0.5f * acc[a][b] + bias;
                Out[(size_t)grow * 64 + j] = v > 0.f ? v : 0.f;
            }
        }
    }
}

// ---------------- pooling: per-block LDS [G][64] accumulator ----------------
__global__ __launch_bounds__(256) void pool_partial(const float* __restrict__ H,
                                                    const int* __restrict__ batch,
                                                    float* __restrict__ psum,
                                                    float* __restrict__ pcnt, int n) {
    __shared__ float ls[GG * 64];
    __shared__ float lc[GG];
    int t = threadIdx.x;
    for (int i = t; i < GG * 64; i += 256) ls[i] = 0.f;
    for (int i = t; i < GG; i += 256) lc[i] = 0.f;
    __syncthreads();
    int chunk = (n + gridDim.x - 1) / gridDim.x;
    int base = blockIdx.x * chunk;
    int end = base + chunk; if (end > n) end = n;
    int f = t & 63, r = t >> 6;
    for (int node = base + r; node < end; node += 4) {
        int g = batch[node];
        float v = H[(size_t)node * 64 + f];
        atomicAdd(&ls[g * 64 + f], v);
        if (f == 0) atomicAdd(&lc[g], 1.f);
    }
    __syncthreads();
    for (int i = t; i < GG * 64; i += 256) {
        float v = ls[i];
        if (v != 0.f) atomicAdd(&psum[i], v);
    }
    for (int i = t; i < GG; i += 256) {
        float v = lc[i];
        if (v != 0.f) atomicAdd(&pcnt[i], v);
    }
}

// ---------------- head ----------------
__global__ __launch_bounds__(256) void pool_final(const float* __restrict__ psum,
                                                  const float* __restrict__ pcnt,
                                                  const float* __restrict__ PW,
                                                  const float* __restrict__ Pb,
                                                  float* __restrict__ out) {
    int t = blockIdx.x * 256 + threadIdx.x;
    int g = t >> 4, o = t & 15;
    if (g >= GG) return;
    float inv = 1.f / fmaxf(pcnt[g], 1.f);
    float acc = 0.f;
#pragma unroll 8
    for (int k = 0; k < 64; k++) acc += psum[g * 64 + k] * PW[o * 64 + k];
    out[t] = acc * inv + Pb[o];
}

extern "C" void kernel_launch(void* const* d_in, const int* in_sizes, int n_in,
                              void* d_out, int out_size, void* d_ws, size_t ws_size,
                              hipStream_t stream) {
    const float* x      = (const float*)d_in[0];
    const int*   ei     = (const int*)d_in[1];
    const int*   batch  = (const int*)d_in[2];
    const float* l0f_Wl = (const float*)d_in[4];
    const float* l0f_bl = (const float*)d_in[5];
    const float* l0f_Wr = (const float*)d_in[6];
    const float* l0b_Wl = (const float*)d_in[7];
    const float* l0b_bl = (const float*)d_in[8];
    const float* l0b_Wr = (const float*)d_in[9];
    const float* l1f_Wl = (const float*)d_in[10];
    const float* l1f_bl = (const float*)d_in[11];
    const float* l1f_Wr = (const float*)d_in[12];
    const float* l1b_Wl = (const float*)d_in[13];
    const float* l1b_bl = (const float*)d_in[14];
    const float* l1b_Wr = (const float*)d_in[15];
    const float* pred_W = (const float*)d_in[16];
    const float* pred_b = (const float*)d_in[17];

    const int n = in_sizes[0] / 64;
    const int e = in_sizes[1] / 2;
    const size_t N64 = (size_t)n * 64;
    const int nb = (n + 255) / 256;

    float* ws   = (float*)d_ws;
    float* aggf = ws;                      // [n][64]
    float* aggb = aggf + N64;              // [n][64]
    float* h0   = aggb + N64;              // [n][64]
    // ---- zero region start ----
    int*   degf = (int*)(h0 + N64);        // [n]
    int*   degb = degf + n;                // [n]
    float* psum = (float*)(degb + n);      // [G][64]
    float* pcnt = psum + GG * 64;          // [G]
    // ---- zero region end ----
    int*   off_f = (int*)(pcnt + GG);      // [n+1]
    int*   off_b = off_f + (n + 1);        // [n+1]
    int*   cur_f = off_b + (n + 1);        // [n]
    int*   cur_b = cur_f + n;              // [n]
    int*   csr_f = cur_b + n;              // [e]
    int*   csr_b = csr_f + e;              // [e]
    int*   part_f = csr_b + e;             // [512]
    int*   part_b = part_f + 512;          // [512]
    float* invf  = (float*)(part_b + 512); // [n]
    float* invb  = invf + n;               // [n]
    float* h1    = aggf;                   // alias (safe: per-block read-before-write)

    size_t zbytes = (2 * (size_t)n + GG * 64 + GG) * sizeof(float);
    hipMemsetAsync(degf, 0, zbytes, stream);

    // degrees + CSR build (once; reused by both layers)
    deg_kernel<<<(e + 255) / 256, 256, 0, stream>>>(ei, degf, degb, e);
    scan1<<<nb, 256, 0, stream>>>(degf, part_f, n);
    scan1<<<nb, 256, 0, stream>>>(degb, part_b, n);
    scan2<<<1, 512, 0, stream>>>(part_f, nb);
    scan2<<<1, 512, 0, stream>>>(part_b, nb);
    scan3<<<nb, 256, 0, stream>>>(degf, part_f, off_f, n, e);
    scan3<<<nb, 256, 0, stream>>>(degb, part_b, off_b, n, e);
    init_cur_inv<<<nb, 256, 0, stream>>>(off_f, off_b, degf, degb,
                                         cur_f, cur_b, invf, invb, n);
    fill_csr<<<(e + 255) / 256, 256, 0, stream>>>(ei, cur_f, cur_b, csr_f, csr_b, e);

    // layer 0
    gather_mean<<<((size_t)n * 16 + 255) / 256, 256, 0, stream>>>(
        x, off_f, csr_f, invf, off_b, csr_b, invb, aggf, aggb, n);
    fused_sage<<<(n + 63) / 64, 256, 0, stream>>>(x, aggf, aggb,
        l0f_Wl, l0f_bl, l0f_Wr, l0b_Wl, l0b_bl, l0b_Wr, h0, n);

    // layer 1
    gather_mean<<<((size_t)n * 16 + 255) / 256, 256, 0, stream>>>(
        h0, off_f, csr_f, invf, off_b, csr_b, invb, aggf, aggb, n);
    fused_sage<<<(n + 63) / 64, 256, 0, stream>>>(h0, aggf, aggb,
        l1f_Wl, l1f_bl, l1f_Wr, l1b_Wl, l1b_bl, l1b_Wr, h1, n);

    // pooling + head
    pool_partial<<<256, 256, 0, stream>>>(h1, batch, psum, pcnt, n);
    pool_final<<<8, 256, 0, stream>>>(psum, pcnt, pred_W, pred_b, (float*)d_out);
}

// Round 3
// 425.255 us; speedup vs baseline: 8.5869x; 1.3869x over previous
//
#include <hip/hip_runtime.h>
#include <hip/hip_bf16.h>

#define GG 128   // num_graphs (static in problem)

// ---------------- degrees + per-edge ranks (returning atomics, coalesced) ----
__global__ __launch_bounds__(256) void deg_rank(const int* __restrict__ ei,
                                                int* __restrict__ degf,
                                                int* __restrict__ degb,
                                                int* __restrict__ rankf,
                                                int* __restrict__ rankb, int e) {
    int i = blockIdx.x * 256 + threadIdx.x;
    if (i >= e) return;
    int s = ei[i], d = ei[e + i];
    rankf[i] = atomicAdd(degf + d, 1);
    rankb[i] = atomicAdd(degb + s, 1);
}

// ---------------- 3-phase exclusive scan (f and b in one launch) ------------
__global__ __launch_bounds__(256) void scan1(const int* __restrict__ degf,
                                             const int* __restrict__ degb,
                                             int* __restrict__ part_f,
                                             int* __restrict__ part_b, int n) {
    const int* deg = blockIdx.y ? degb : degf;
    int* partial = blockIdx.y ? part_b : part_f;
    __shared__ int s[256];
    int t = threadIdx.x, i = blockIdx.x * 256 + t;
    s[t] = (i < n) ? deg[i] : 0;
    __syncthreads();
    for (int o = 128; o > 0; o >>= 1) {
        if (t < o) s[t] += s[t + o];
        __syncthreads();
    }
    if (t == 0) partial[blockIdx.x] = s[0];
}

__global__ __launch_bounds__(512) void scan2(int* __restrict__ part_f,
                                             int* __restrict__ part_b, int nb) {
    int* partial = blockIdx.x ? part_b : part_f;
    __shared__ int s[512];
    int t = threadIdx.x;
    int v = (t < nb) ? partial[t] : 0;
    s[t] = v;
    __syncthreads();
    for (int o = 1; o < 512; o <<= 1) {
        int u = (t >= o) ? s[t - o] : 0;
        __syncthreads();
        s[t] += u;
        __syncthreads();
    }
    if (t < nb) partial[t] = s[t] - v;  // exclusive
}

__global__ __launch_bounds__(256) void scan3(const int* __restrict__ degf,
                                             const int* __restrict__ degb,
                                             const int* __restrict__ part_f,
                                             const int* __restrict__ part_b,
                                             int* __restrict__ off_f,
                                             int* __restrict__ off_b,
                                             float* __restrict__ invf,
                                             float* __restrict__ invb,
                                             int n, int e) {
    const int* deg = blockIdx.y ? degb : degf;
    const int* partial = blockIdx.y ? part_b : part_f;
    int* off = blockIdx.y ? off_b : off_f;
    float* inv = blockIdx.y ? invb : invf;
    __shared__ int s[256];
    int t = threadIdx.x, i = blockIdx.x * 256 + t;
    int v = (i < n) ? deg[i] : 0;
    s[t] = v;
    __syncthreads();
    for (int o = 1; o < 256; o <<= 1) {
        int u = (t >= o) ? s[t - o] : 0;
        __syncthreads();
        s[t] += u;
        __syncthreads();
    }
    if (i < n) {
        off[i] = partial[blockIdx.x] + s[t] - v;
        inv[i] = 1.f / fmaxf((float)v, 1.f);
    }
    if (i == n - 1) off[n] = e;
}

// ---------------- CSR fill: atomic-free scattered stores --------------------
__global__ __launch_bounds__(256) void fill_csr(const int* __restrict__ ei,
                                                const int* __restrict__ off_f,
                                                const int* __restrict__ off_b,
                                                const int* __restrict__ rankf,
                                                const int* __restrict__ rankb,
                                                int* __restrict__ csr_f,
                                                int* __restrict__ csr_b, int e) {
    int i = blockIdx.x * 256 + threadIdx.x;
    if (i >= e) return;
    int s = ei[i], d = ei[e + i];
    csr_f[off_f[d] + rankf[i]] = s;
    csr_b[off_b[s] + rankb[i]] = d;
}

// ---------------- gather-mean: 32 threads/node (16 per direction) -----------
__global__ __launch_bounds__(256) void gather_mean(
    const float* __restrict__ X,
    const int* __restrict__ off_f, const int* __restrict__ csr_f,
    const float* __restrict__ invf,
    const int* __restrict__ off_b, const int* __restrict__ csr_b,
    const float* __restrict__ invb,
    float* __restrict__ aggf, float* __restrict__ aggb, int n) {
    int tid = blockIdx.x * 256 + threadIdx.x;
    int node = tid >> 5;
    if (node >= n) return;
    int dir = (tid >> 4) & 1;
    int c = (tid & 15) * 4;
    const int* off = dir ? off_b : off_f;
    const int* csr = dir ? csr_b : csr_f;
    const float* inv = dir ? invb : invf;
    float* agg = dir ? aggb : aggf;

    int b = off[node], en = off[node + 1];
    float4 acc = make_float4(0.f, 0.f, 0.f, 0.f);
    int k = b;
    for (; k + 3 < en; k += 4) {
        int n0 = csr[k], n1 = csr[k + 1], n2 = csr[k + 2], n3 = csr[k + 3];
        float4 v0 = *reinterpret_cast<const float4*>(X + (size_t)n0 * 64 + c);
        float4 v1 = *reinterpret_cast<const float4*>(X + (size_t)n1 * 64 + c);
        float4 v2 = *reinterpret_cast<const float4*>(X + (size_t)n2 * 64 + c);
        float4 v3 = *reinterpret_cast<const float4*>(X + (size_t)n3 * 64 + c);
        acc.x += v0.x + v1.x + v2.x + v3.x;
        acc.y += v0.y + v1.y + v2.y + v3.y;
        acc.z += v0.z + v1.z + v2.z + v3.z;
        acc.w += v0.w + v1.w + v2.w + v3.w;
    }
    for (; k < en; k++) {
        int s = csr[k];
        float4 v = *reinterpret_cast<const float4*>(X + (size_t)s * 64 + c);
        acc.x += v.x; acc.y += v.y; acc.z += v.z; acc.w += v.w;
    }
    float iv = inv[node];
    float4 r = make_float4(acc.x * iv, acc.y * iv, acc.z * iv, acc.w * iv);
    *reinterpret_cast<float4*>(agg + (size_t)node * 64 + c) = r;
}

// ---------------- fused bidirectional SAGE layer ----------------
// out = relu(0.5*(mean_f@Wlf^T + mean_b@Wlb^T + x@(Wrf+Wrb)^T + blf+blb))
__global__ __launch_bounds__(256) void fused_sage(
    const float* __restrict__ X,
    const float* __restrict__ aggf, const float* __restrict__ aggb,
    const float* __restrict__ Wlf, const float* __restrict__ blf,
    const float* __restrict__ Wrf,
    const float* __restrict__ Wlb, const float* __restrict__ blb,
    const float* __restrict__ Wrb,
    float* __restrict__ Out, int n)
{
    __shared__ float sIn[64][68];
    __shared__ float sW[64][68];
    const int t = threadIdx.x;
    const int base = blockIdx.x * 64;
    const int jg = t & 15;
    const int ng = t >> 4;

    float acc[4][4];
#pragma unroll
    for (int a = 0; a < 4; a++)
#pragma unroll
        for (int b = 0; b < 4; b++) acc[a][b] = 0.f;

    for (int p = 0; p < 3; p++) {
        const float* src = (p == 0) ? aggf : (p == 1) ? aggb : X;
#pragma unroll
        for (int i = 0; i < 4; i++) {
            int f4 = t + 256 * i;
            int row = f4 >> 4, c4 = f4 & 15;
            int grow = base + row;
            float4 v = make_float4(0.f, 0.f, 0.f, 0.f);
            if (grow < n)
                v = *reinterpret_cast<const float4*>(src + (size_t)grow * 64 + c4 * 4);
            *reinterpret_cast<float4*>(&sIn[row][c4 * 4]) = v;
        }
#pragma unroll
        for (int i = 0; i < 4; i++) {
            int f4 = t + 256 * i;
            int row = f4 >> 4, c4 = f4 & 15;
            float4 w;
            if (p == 0) w = *reinterpret_cast<const float4*>(Wlf + row * 64 + c4 * 4);
            else if (p == 1) w = *reinterpret_cast<const float4*>(Wlb + row * 64 + c4 * 4);
            else {
                float4 w1 = *reinterpret_cast<const float4*>(Wrf + row * 64 + c4 * 4);
                float4 w2 = *reinterpret_cast<const float4*>(Wrb + row * 64 + c4 * 4);
                w = make_float4(w1.x + w2.x, w1.y + w2.y, w1.z + w2.z, w1.w + w2.w);
            }
            *reinterpret_cast<float4*>(&sW[row][c4 * 4]) = w;
        }
        __syncthreads();
        for (int kc = 0; kc < 16; kc++) {
            float4 av[4], wv[4];
#pragma unroll
            for (int i = 0; i < 4; i++)
                av[i] = *reinterpret_cast<const float4*>(&sIn[ng + 16 * i][kc * 4]);
#pragma unroll
            for (int i = 0; i < 4; i++)
                wv[i] = *reinterpret_cast<const float4*>(&sW[jg + 16 * i][kc * 4]);
#pragma unroll
            for (int a = 0; a < 4; a++)
#pragma unroll
                for (int b = 0; b < 4; b++)
                    acc[a][b] += av[a].x * wv[b].x + av[a].y * wv[b].y +
                                 av[a].z * wv[b].z + av[a].w * wv[b].w;
        }
        __syncthreads();
    }
#pragma unroll
    for (int b = 0; b < 4; b++) {
        int j = jg + 16 * b;
        float bias = 0.5f * (blf[j] + blb[j]);
#pragma unroll
        for (int a = 0; a < 4; a++) {
            int grow = base + ng + 16 * a;
            if (grow < n) {
                float v = 0.5f * acc[a][b] + bias;
                Out[(size_t)grow * 64 + j] = v > 0.f ? v : 0.f;
            }
        }
    }
}

// ---------------- pooling: per-block LDS [G][64] accumulator ----------------
__global__ __launch_bounds__(256) void pool_partial(const float* __restrict__ H,
                                                    const int* __restrict__ batch,
                                                    float* __restrict__ psum,
                                                    float* __restrict__ pcnt, int n) {
    __shared__ float ls[GG * 64];
    __shared__ float lc[GG];
    int t = threadIdx.x;
    for (int i = t; i < GG * 64; i += 256) ls[i] = 0.f;
    for (int i = t; i < GG; i += 256) lc[i] = 0.f;
    __syncthreads();
    int chunk = (n + gridDim.x - 1) / gridDim.x;
    int base = blockIdx.x * chunk;
    int end = base + chunk; if (end > n) end = n;
    int f = t & 63, r = t >> 6;
    for (int node = base + r; node < end; node += 4) {
        int g = batch[node];
        float v = H[(size_t)node * 64 + f];
        atomicAdd(&ls[g * 64 + f], v);
        if (f == 0) atomicAdd(&lc[g], 1.f);
    }
    __syncthreads();
    for (int i = t; i < GG * 64; i += 256) {
        float v = ls[i];
        if (v != 0.f) atomicAdd(&psum[i], v);
    }
    for (int i = t; i < GG; i += 256) {
        float v = lc[i];
        if (v != 0.f) atomicAdd(&pcnt[i], v);
    }
}

// ---------------- head ----------------
__global__ __launch_bounds__(256) void pool_final(const float* __restrict__ psum,
                                                  const float* __restrict__ pcnt,
                                                  const float* __restrict__ PW,
                                                  const float* __restrict__ Pb,
                                                  float* __restrict__ out) {
    int t = blockIdx.x * 256 + threadIdx.x;
    int g = t >> 4, o = t & 15;
    if (g >= GG) return;
    float inv = 1.f / fmaxf(pcnt[g], 1.f);
    float acc = 0.f;
#pragma unroll 8
    for (int k = 0; k < 64; k++) acc += psum[g * 64 + k] * PW[o * 64 + k];
    out[t] = acc * inv + Pb[o];
}

extern "C" void kernel_launch(void* const* d_in, const int* in_sizes, int n_in,
                              void* d_out, int out_size, void* d_ws, size_t ws_size,
                              hipStream_t stream) {
    const float* x      = (const float*)d_in[0];
    const int*   ei     = (const int*)d_in[1];
    const int*   batch  = (const int*)d_in[2];
    const float* l0f_Wl = (const float*)d_in[4];
    const float* l0f_bl = (const float*)d_in[5];
    const float* l0f_Wr = (const float*)d_in[6];
    const float* l0b_Wl = (const float*)d_in[7];
    const float* l0b_bl = (const float*)d_in[8];
    const float* l0b_Wr = (const float*)d_in[9];
    const float* l1f_Wl = (const float*)d_in[10];
    const float* l1f_bl = (const float*)d_in[11];
    const float* l1f_Wr = (const float*)d_in[12];
    const float* l1b_Wl = (const float*)d_in[13];
    const float* l1b_bl = (const float*)d_in[14];
    const float* l1b_Wr = (const float*)d_in[15];
    const float* pred_W = (const float*)d_in[16];
    const float* pred_b = (const float*)d_in[17];

    const int n = in_sizes[0] / 64;
    const int e = in_sizes[1] / 2;
    const size_t N64 = (size_t)n * 64;
    const int nb = (n + 255) / 256;

    float* ws   = (float*)d_ws;
    float* aggf = ws;                      // [n][64]  (ranks alias here pre-gather)
    float* aggb = aggf + N64;              // [n][64]
    float* h0   = aggb + N64;              // [n][64]
    // ---- zero region start ----
    int*   degf = (int*)(h0 + N64);        // [n]
    int*   degb = degf + n;                // [n]
    float* psum = (float*)(degb + n);      // [G][64]
    float* pcnt = psum + GG * 64;          // [G]
    // ---- zero region end ----
    int*   off_f = (int*)(pcnt + GG);      // [n+1]
    int*   off_b = off_f + (n + 1);        // [n+1]
    int*   csr_f = off_b + (n + 1);        // [e]
    int*   csr_b = csr_f + e;              // [e]
    int*   part_f = csr_b + e;             // [512]
    int*   part_b = part_f + 512;          // [512]
    float* invf  = (float*)(part_b + 512); // [n]
    float* invb  = invf + n;               // [n]
    // ranks alias the aggf/aggb region (dead before gather_mean writes it)
    int*   rankf = (int*)aggf;             // [e]
    int*   rankb = rankf + e;              // [e]
    float* h1    = aggf;                   // alias (safe: per-block read-before-write)

    size_t zbytes = (2 * (size_t)n + GG * 64 + GG) * sizeof(float);
    hipMemsetAsync(degf, 0, zbytes, stream);

    // CSR build (once; reused by both layers)
    deg_rank<<<(e + 255) / 256, 256, 0, stream>>>(ei, degf, degb, rankf, rankb, e);
    scan1<<<dim3(nb, 2), 256, 0, stream>>>(degf, degb, part_f, part_b, n);
    scan2<<<2, 512, 0, stream>>>(part_f, part_b, nb);
    scan3<<<dim3(nb, 2), 256, 0, stream>>>(degf, degb, part_f, part_b,
                                           off_f, off_b, invf, invb, n, e);
    fill_csr<<<(e + 255) / 256, 256, 0, stream>>>(ei, off_f, off_b, rankf, rankb,
                                                  csr_f, csr_b, e);

    // layer 0
    gather_mean<<<((size_t)n * 32 + 255) / 256, 256, 0, stream>>>(
        x, off_f, csr_f, invf, off_b, csr_b, invb, aggf, aggb, n);
    fused_sage<<<(n + 63) / 64, 256, 0, stream>>>(x, aggf, aggb,
        l0f_Wl, l0f_bl, l0f_Wr, l0b_Wl, l0b_bl, l0b_Wr, h0, n);

    // layer 1
    gather_mean<<<((size_t)n * 32 + 255) / 256, 256, 0, stream>>>(
        h0, off_f, csr_f, invf, off_b, csr_b, invb, aggf, aggb, n);
    fused_sage<<<(n + 63) / 64, 256, 0, stream>>>(h0, aggf, aggb,
        l1f_Wl, l1f_bl, l1f_Wr, l1b_Wl, l1b_bl, l1b_Wr, h1, n);

    // pooling + head
    pool_partial<<<256, 256, 0, stream>>>(h1, batch, psum, pcnt, n);
    pool_final<<<8, 256, 0, stream>>>(psum, pcnt, pred_W, pred_b, (float*)d_out);
}